// Round 1
// baseline (2881.603 us; speedup 1.0000x reference)
//
#include <hip/hip_runtime.h>
#include <stdint.h>

// Geometry: B=2, N=5120, F=10240, H=W=256 (derived from in_sizes where cheap).
// Pipeline (bit-exact fp32 replication of the JAX/numpy reference):
//   1) transform verts with cam_new -> raster positions (x,y clipped, z=-t2+10)
//      and with cam -> uv attributes (u,v clipped)
//   2) per-face precompute: v0, edge vectors, inv=1/d (NaN if |d|<=1e-8), z's,
//      bbox, and per-vertex uv attrs
//   3) per-pixel z-buffer over all faces in index order (strict z<best ==
//      ref's chunked argmin-first + strict cross-chunk), then fused bilinear
//      grid_sample of the input image at the interpolated uv.

struct __align__(16) FaceHot {
  // bbox first so the cull only needs the first 16 bytes
  float xmin, xmax, ymin, ymax;
  float v0x, v0y, e1x, e1y, e2x, e2y, inv;
  float z0, z1, z2;
  float pad0, pad1;
};

struct __align__(16) FaceAttr {
  float u0, v0, u1, v1, u2, v2, pad0, pad1;
};

__device__ __forceinline__ float clip11(float t) {
  return fminf(1.0f, fmaxf(-1.0f, t));
}

__global__ void k_transform(const float* __restrict__ hv,
                            const float* __restrict__ cam,
                            const float* __restrict__ camn,
                            float* __restrict__ pos,   // B*N*4
                            float* __restrict__ uv,    // B*N*2
                            int N, int B) {
#pragma clang fp contract(off)
  int t = blockIdx.x * 256 + threadIdx.x;
  if (t >= B * N) return;
  int b = t / N;
  float X0 = hv[t * 3 + 0];
  float X1 = hv[t * 3 + 1];
  float X2 = hv[t * 3 + 2];
  {
    float c0 = camn[b * 3 + 0], c1 = camn[b * 3 + 1], c2 = camn[b * 3 + 2];
    float t0 = c0 * (X0 + c1);
    float t1 = c0 * (X1 + c2);
    float t2 = c0 * X2;
    float x = clip11(t0);
    float y = clip11(-t1);
    float z = -t2 + 10.0f;
    pos[t * 4 + 0] = x;
    pos[t * 4 + 1] = y;
    pos[t * 4 + 2] = z;
    pos[t * 4 + 3] = 0.0f;
  }
  {
    float c0 = cam[b * 3 + 0], c1 = cam[b * 3 + 1], c2 = cam[b * 3 + 2];
    float t0 = c0 * (X0 + c1);
    float t1 = c0 * (X1 + c2);
    float u = clip11(t0);
    float v = clip11(-t1);
    uv[t * 2 + 0] = u;
    uv[t * 2 + 1] = v;
  }
}

__global__ void k_faces(const int* __restrict__ faces,
                        const float* __restrict__ pos,
                        const float* __restrict__ uv,
                        FaceHot* __restrict__ fh,
                        FaceAttr* __restrict__ fa,
                        int F, int N, int B) {
#pragma clang fp contract(off)
  int t = blockIdx.x * 256 + threadIdx.x;
  if (t >= B * F) return;
  int b = t / F;
  int f = t - b * F;
  int i0 = faces[f * 3 + 0];
  int i1 = faces[f * 3 + 1];
  int i2 = faces[f * 3 + 2];
  const float* p0 = pos + (size_t)(b * N + i0) * 4;
  const float* p1 = pos + (size_t)(b * N + i1) * 4;
  const float* p2 = pos + (size_t)(b * N + i2) * 4;
  float x0 = p0[0], y0 = p0[1], z0 = p0[2];
  float x1 = p1[0], y1 = p1[1], z1 = p1[2];
  float x2 = p2[0], y2 = p2[1], z2 = p2[2];
  float e1x = x1 - x0;
  float e1y = y1 - y0;
  float e2x = x2 - x0;
  float e2y = y2 - y0;
  float m1 = e1x * e2y;
  float m2 = e2x * e1y;
  float d = m1 - m2;
  float inv;
  if (fabsf(d) > 1e-8f) {
    inv = 1.0f / d;   // IEEE-correct division (no fast-math)
  } else {
    inv = __int_as_float(0x7fc00000);  // NaN => w1,w2 NaN => inside false
  }
  FaceHot h;
  h.xmin = fminf(x0, fminf(x1, x2));
  h.xmax = fmaxf(x0, fmaxf(x1, x2));
  h.ymin = fminf(y0, fminf(y1, y2));
  h.ymax = fmaxf(y0, fmaxf(y1, y2));
  h.v0x = x0; h.v0y = y0;
  h.e1x = e1x; h.e1y = e1y;
  h.e2x = e2x; h.e2y = e2y;
  h.inv = inv;
  h.z0 = z0; h.z1 = z1; h.z2 = z2;
  h.pad0 = 0.0f; h.pad1 = 0.0f;
  fh[t] = h;
  FaceAttr a;
  a.u0 = uv[(size_t)(b * N + i0) * 2 + 0];
  a.v0 = uv[(size_t)(b * N + i0) * 2 + 1];
  a.u1 = uv[(size_t)(b * N + i1) * 2 + 0];
  a.v1 = uv[(size_t)(b * N + i1) * 2 + 1];
  a.u2 = uv[(size_t)(b * N + i2) * 2 + 0];
  a.v2 = uv[(size_t)(b * N + i2) * 2 + 1];
  a.pad0 = 0.0f; a.pad1 = 0.0f;
  fa[t] = a;
}

__device__ __forceinline__ float fetchpix(const float* __restrict__ img, int base,
                                          float ixf, float iyf) {
  bool valid = (ixf >= 0.0f) && (ixf < 256.0f) && (iyf >= 0.0f) && (iyf < 256.0f);
  int ix = (int)fminf(255.0f, fmaxf(0.0f, ixf));
  int iy = (int)fminf(255.0f, fmaxf(0.0f, iyf));
  float v = img[base + iy * 256 + ix];
  return valid ? v : 0.0f;
}

__global__ void __launch_bounds__(256) k_raster(const FaceHot* __restrict__ fh,
                                                const FaceAttr* __restrict__ fa,
                                                const float* __restrict__ img,
                                                float* __restrict__ out,
                                                int F) {
#pragma clang fp contract(off)
  int bi = blockIdx.x;      // b*256 + row
  int b = bi >> 8;
  int i = bi & 255;
  int j = threadIdx.x;
  float px = (j + 0.5f) / 256.0f * 2.0f - 1.0f;   // exact
  float py = (i + 0.5f) / 256.0f * 2.0f - 1.0f;   // exact, wave-uniform
  int wv = threadIdx.x >> 6;
  float pxlo = (wv * 64 + 0.5f) / 256.0f * 2.0f - 1.0f;
  float pxhi = (wv * 64 + 63 + 0.5f) / 256.0f * 2.0f - 1.0f;

  const FaceHot* __restrict__ fb = fh + (size_t)b * F;

  float bestz = 1000000.0f;
  int bestf = -1;
  float bw0 = 0.0f, bw1 = 0.0f, bw2 = 0.0f;

  for (int f = 0; f < F; ++f) {
    const FaceHot& fd = fb[f];
    // wave-uniform conservative bbox cull (py, pxlo, pxhi are wave-uniform)
    if (!(fd.ymin <= py && fd.ymax >= py && fd.xmin <= pxhi && fd.xmax >= pxlo))
      continue;
    float dpx = px - fd.v0x;
    float dpy = py - fd.v0y;
    float w1 = (dpx * fd.e2y - fd.e2x * dpy) * fd.inv;
    float w2 = (fd.e1x * dpy - dpx * fd.e1y) * fd.inv;
    float w0 = (1.0f - w1) - w2;
    if (w0 >= 0.0f && w1 >= 0.0f && w2 >= 0.0f) {
      float z = (w0 * fd.z0 + w1 * fd.z1) + w2 * fd.z2;
      if (z < bestz) {   // strict: first index wins ties, matches ref scan
        bestz = z;
        bestf = f;
        bw0 = w0; bw1 = w1; bw2 = w2;
      }
    }
  }

  float gx = 0.0f, gy = 0.0f;
  if (bestf >= 0) {
    FaceAttr a = fa[(size_t)b * F + bestf];
    gx = (bw0 * a.u0 + bw1 * a.u1) + bw2 * a.u2;
    gy = (bw0 * a.v0 + bw1 * a.v1) + bw2 * a.v2;
  }

  // grid_sample (align_corners=False, zero padding), exact ref rounding order
  float x = (gx + 1.0f) * 0.5f * 256.0f - 0.5f;
  float y = (gy + 1.0f) * 0.5f * 256.0f - 0.5f;
  float x0f = floorf(x), y0f = floorf(y);
  float wx1 = x - x0f, wx0 = 1.0f - wx1;
  float wy1 = y - y0f, wy0 = 1.0f - wy1;

  int pix = i * 256 + j;
  for (int c = 0; c < 3; ++c) {
    int base = (b * 3 + c) * 65536;
    float f00 = fetchpix(img, base, x0f, y0f);
    float f10 = fetchpix(img, base, x0f + 1.0f, y0f);
    float f01 = fetchpix(img, base, x0f, y0f + 1.0f);
    float f11 = fetchpix(img, base, x0f + 1.0f, y0f + 1.0f);
    float A = wy0 * ((wx0 * f00) + (wx1 * f10));
    float Bv = wy1 * ((wx0 * f01) + (wx1 * f11));
    out[base + pix] = A + Bv;
  }
}

extern "C" void kernel_launch(void* const* d_in, const int* in_sizes, int n_in,
                              void* d_out, int out_size, void* d_ws, size_t ws_size,
                              hipStream_t stream) {
  const float* cam  = (const float*)d_in[0];
  const float* hv   = (const float*)d_in[1];
  const float* img  = (const float*)d_in[2];
  const float* camn = (const float*)d_in[3];
  const int* faces  = (const int*)d_in[4];

  const int B = in_sizes[0] / 3;            // 2
  const int N = in_sizes[1] / (3 * B);      // 5120
  const int F = in_sizes[4] / 3;            // 10240

  float* ws = (float*)d_ws;
  float* pos = ws;                          // B*N*4 floats
  float* uv  = pos + (size_t)B * N * 4;     // B*N*2 floats
  size_t off = (size_t)B * N * 4 + (size_t)B * N * 2;
  off = (off + 15) & ~(size_t)15;
  FaceHot* fh = (FaceHot*)(ws + off);                       // B*F*16 floats
  FaceAttr* fa = (FaceAttr*)((float*)fh + (size_t)B * F * 16);  // B*F*8 floats

  int nv = B * N;
  k_transform<<<(nv + 255) / 256, 256, 0, stream>>>(hv, cam, camn, pos, uv, N, B);
  int nf = B * F;
  k_faces<<<(nf + 255) / 256, 256, 0, stream>>>(faces, pos, uv, fh, fa, F, N, B);
  k_raster<<<B * 256, 256, 0, stream>>>(fh, fa, img, (float*)d_out, F);
}

// Round 2
// 545.067 us; speedup vs baseline: 5.2867x; 5.2867x over previous
//
#include <hip/hip_runtime.h>
#include <stdint.h>

typedef unsigned long long ull;

// Geometry: B=2, N=5120, F=10240, H=W=256.
// Bit-exact fp32 replication of the JAX/numpy reference (contract off, IEEE div).
// Face record = 4 float4: q0={xmin,xmax,ymin,ymax} q1={v0x,v0y,e1x,e1y}
//                         q2={e2x,e2y,inv,z0}      q3={z1,z2,0,0}
// Attr record = 2 float4: a0={u0,v0,u1,v1} a1={u2,v2,0,0}
// Winner selection: packed u64 = (bits(z)<<32)|f, device atomicMin ->
// lexicographic (z, then smallest f) == reference chunked-argmin + strict '<'.

__device__ __forceinline__ float clip11(float t) {
  return fminf(1.0f, fmaxf(-1.0f, t));
}

__global__ void k_init(ull* __restrict__ packed, int n) {
  int t = blockIdx.x * 256 + threadIdx.x;
  if (t < n) packed[t] = 0xFFFFFFFFFFFFFFFFull;
}

__global__ void k_transform(const float* __restrict__ hv,
                            const float* __restrict__ cam,
                            const float* __restrict__ camn,
                            float* __restrict__ pos,   // B*N*4
                            float* __restrict__ uv,    // B*N*2
                            int N, int B) {
#pragma clang fp contract(off)
  int t = blockIdx.x * 256 + threadIdx.x;
  if (t >= B * N) return;
  int b = t / N;
  float X0 = hv[t * 3 + 0];
  float X1 = hv[t * 3 + 1];
  float X2 = hv[t * 3 + 2];
  {
    float c0 = camn[b * 3 + 0], c1 = camn[b * 3 + 1], c2 = camn[b * 3 + 2];
    float t0 = c0 * (X0 + c1);
    float t1 = c0 * (X1 + c2);
    float t2 = c0 * X2;
    pos[t * 4 + 0] = clip11(t0);
    pos[t * 4 + 1] = clip11(-t1);
    pos[t * 4 + 2] = -t2 + 10.0f;
    pos[t * 4 + 3] = 0.0f;
  }
  {
    float c0 = cam[b * 3 + 0], c1 = cam[b * 3 + 1], c2 = cam[b * 3 + 2];
    float t0 = c0 * (X0 + c1);
    float t1 = c0 * (X1 + c2);
    uv[t * 2 + 0] = clip11(t0);
    uv[t * 2 + 1] = clip11(-t1);
  }
}

__global__ void k_faces(const int* __restrict__ faces,
                        const float* __restrict__ pos,
                        const float* __restrict__ uv,
                        float4* __restrict__ fh4,   // B*F*4
                        float4* __restrict__ fa4,   // B*F*2
                        int F, int N, int B) {
#pragma clang fp contract(off)
  int t = blockIdx.x * 256 + threadIdx.x;
  if (t >= B * F) return;
  int b = t / F;
  int f = t - b * F;
  int i0 = faces[f * 3 + 0];
  int i1 = faces[f * 3 + 1];
  int i2 = faces[f * 3 + 2];
  const float* p0 = pos + (size_t)(b * N + i0) * 4;
  const float* p1 = pos + (size_t)(b * N + i1) * 4;
  const float* p2 = pos + (size_t)(b * N + i2) * 4;
  float x0 = p0[0], y0 = p0[1], z0 = p0[2];
  float x1 = p1[0], y1 = p1[1], z1 = p1[2];
  float x2 = p2[0], y2 = p2[1], z2 = p2[2];
  float e1x = x1 - x0;
  float e1y = y1 - y0;
  float e2x = x2 - x0;
  float e2y = y2 - y0;
  float d = (e1x * e2y) - (e2x * e1y);
  float inv;
  if (fabsf(d) > 1e-8f) {
    inv = 1.0f / d;                     // IEEE division
  } else {
    inv = __int_as_float(0x7fc00000);   // NaN -> inside test fails
  }
  float4 q0 = make_float4(fminf(x0, fminf(x1, x2)), fmaxf(x0, fmaxf(x1, x2)),
                          fminf(y0, fminf(y1, y2)), fmaxf(y0, fmaxf(y1, y2)));
  float4 q1 = make_float4(x0, y0, e1x, e1y);
  float4 q2 = make_float4(e2x, e2y, inv, z0);
  float4 q3 = make_float4(z1, z2, 0.0f, 0.0f);
  float4* fq = fh4 + (size_t)t * 4;
  fq[0] = q0; fq[1] = q1; fq[2] = q2; fq[3] = q3;

  float u0 = uv[(size_t)(b * N + i0) * 2 + 0];
  float v0 = uv[(size_t)(b * N + i0) * 2 + 1];
  float u1 = uv[(size_t)(b * N + i1) * 2 + 0];
  float v1 = uv[(size_t)(b * N + i1) * 2 + 1];
  float u2 = uv[(size_t)(b * N + i2) * 2 + 0];
  float v2 = uv[(size_t)(b * N + i2) * 2 + 1];
  float4* aq = fa4 + (size_t)t * 2;
  aq[0] = make_float4(u0, v0, u1, v1);
  aq[1] = make_float4(u2, v2, 0.0f, 0.0f);
}

#define CHUNK 128

__global__ void __launch_bounds__(256) k_raster(const float4* __restrict__ fh4,
                                                ull* __restrict__ packed,
                                                int F, int S, int segF) {
#pragma clang fp contract(off)
  int blk = blockIdx.x;
  int row = blk & 255;
  int bs = blk >> 8;            // b*S + s
  int b = bs / S;
  int s = bs - b * S;
  int f0 = s * segF;
  int f1 = min(F, f0 + segF);
  int j = threadIdx.x;

  float px = (j + 0.5f) / 256.0f * 2.0f - 1.0f;
  float py = (row + 0.5f) / 256.0f * 2.0f - 1.0f;   // wave-uniform
  int wv = j >> 6;
  float pxlo = (wv * 64 + 0.5f) / 256.0f * 2.0f - 1.0f;
  float pxhi = (wv * 64 + 63 + 0.5f) / 256.0f * 2.0f - 1.0f;

  const float4* __restrict__ base4 = fh4 + (size_t)b * F * 4;

  __shared__ float4 lds[CHUNK * 4];

  float bestz = 1000000.0f;
  int bestf = -1;

  for (int cb = f0; cb < f1; cb += CHUNK) {
    int nf = min(CHUNK, f1 - cb);
    __syncthreads();
    for (int idx = j; idx < nf * 4; idx += 256)
      lds[idx] = base4[(size_t)cb * 4 + idx];
    __syncthreads();
    for (int k = 0; k < nf; ++k) {
      float4 q0 = lds[k * 4 + 0];
      // wave-uniform conservative bbox cull
      if (!(q0.z <= py && q0.w >= py && q0.x <= pxhi && q0.y >= pxlo))
        continue;
      float4 q1 = lds[k * 4 + 1];
      float4 q2 = lds[k * 4 + 2];
      float dpx = px - q1.x;
      float dpy = py - q1.y;
      float w1 = (dpx * q2.y - q2.x * dpy) * q2.z;
      float w2 = (q1.z * dpy - dpx * q1.w) * q2.z;
      float w0 = (1.0f - w1) - w2;
      if (w0 >= 0.0f && w1 >= 0.0f && w2 >= 0.0f) {
        float4 q3 = lds[k * 4 + 3];
        float z = (w0 * q2.w + w1 * q3.x) + w2 * q3.y;
        if (z < bestz) {          // faces scanned in increasing f within segment
          bestz = z;
          bestf = cb + k;
        }
      }
    }
  }

  if (bestf >= 0) {
    ull pk = ((ull)__float_as_uint(bestz) << 32) | (unsigned int)bestf;
    atomicMin(packed + ((size_t)b << 16) + (row << 8) + j, pk);
  }
}

__device__ __forceinline__ float fetchpix(const float* __restrict__ img, int base,
                                          float ixf, float iyf) {
  bool valid = (ixf >= 0.0f) && (ixf < 256.0f) && (iyf >= 0.0f) && (iyf < 256.0f);
  int ix = (int)fminf(255.0f, fmaxf(0.0f, ixf));
  int iy = (int)fminf(255.0f, fmaxf(0.0f, iyf));
  float v = img[base + iy * 256 + ix];
  return valid ? v : 0.0f;
}

__global__ void __launch_bounds__(256) k_sample(const float4* __restrict__ fh4,
                                                const float4* __restrict__ fa4,
                                                const ull* __restrict__ packed,
                                                const float* __restrict__ img,
                                                float* __restrict__ out,
                                                int F) {
#pragma clang fp contract(off)
  int t = blockIdx.x * 256 + threadIdx.x;   // over B*65536
  int b = t >> 16;
  int pix = t & 65535;
  int row = pix >> 8;
  int col = pix & 255;
  float px = (col + 0.5f) / 256.0f * 2.0f - 1.0f;
  float py = (row + 0.5f) / 256.0f * 2.0f - 1.0f;

  ull pk = packed[t];
  unsigned int f = (unsigned int)pk;
  float gx = 0.0f, gy = 0.0f;
  if (f != 0xFFFFFFFFu) {
    const float4* fq = fh4 + ((size_t)b * F + f) * 4;
    float4 q1 = fq[1];
    float4 q2 = fq[2];
    float dpx = px - q1.x;
    float dpy = py - q1.y;
    float w1 = (dpx * q2.y - q2.x * dpy) * q2.z;   // bit-identical to k_raster
    float w2 = (q1.z * dpy - dpx * q1.w) * q2.z;
    float w0 = (1.0f - w1) - w2;
    const float4* aq = fa4 + ((size_t)b * F + f) * 2;
    float4 a0 = aq[0];
    float4 a1 = aq[1];
    gx = (w0 * a0.x + w1 * a0.z) + w2 * a1.x;
    gy = (w0 * a0.y + w1 * a0.w) + w2 * a1.y;
  }

  // grid_sample (align_corners=False, zero pad), exact ref op order
  float x = (gx + 1.0f) * 0.5f * 256.0f - 0.5f;
  float y = (gy + 1.0f) * 0.5f * 256.0f - 0.5f;
  float x0f = floorf(x), y0f = floorf(y);
  float wx1 = x - x0f, wx0 = 1.0f - wx1;
  float wy1 = y - y0f, wy0 = 1.0f - wy1;

  for (int c = 0; c < 3; ++c) {
    int base = (b * 3 + c) * 65536;
    float f00 = fetchpix(img, base, x0f, y0f);
    float f10 = fetchpix(img, base, x0f + 1.0f, y0f);
    float f01 = fetchpix(img, base, x0f, y0f + 1.0f);
    float f11 = fetchpix(img, base, x0f + 1.0f, y0f + 1.0f);
    float A = wy0 * ((wx0 * f00) + (wx1 * f10));
    float Bv = wy1 * ((wx0 * f01) + (wx1 * f11));
    out[base + pix] = A + Bv;
  }
}

extern "C" void kernel_launch(void* const* d_in, const int* in_sizes, int n_in,
                              void* d_out, int out_size, void* d_ws, size_t ws_size,
                              hipStream_t stream) {
  const float* cam  = (const float*)d_in[0];
  const float* hv   = (const float*)d_in[1];
  const float* img  = (const float*)d_in[2];
  const float* camn = (const float*)d_in[3];
  const int* faces  = (const int*)d_in[4];

  const int B = in_sizes[0] / 3;            // 2
  const int N = in_sizes[1] / (3 * B);      // 5120
  const int F = in_sizes[4] / 3;            // 10240
  const int P = 65536;

  char* wsb = (char*)d_ws;
  float* pos = (float*)wsb;                          // B*N*4 floats
  float* uv  = pos + (size_t)B * N * 4;              // B*N*2 floats
  size_t ofs = ((size_t)B * N * 4 + (size_t)B * N * 2) * 4;
  ofs = (ofs + 255) & ~(size_t)255;
  float4* fh4 = (float4*)(wsb + ofs);  ofs += (size_t)B * F * 4 * sizeof(float4);
  float4* fa4 = (float4*)(wsb + ofs);  ofs += (size_t)B * F * 2 * sizeof(float4);
  ull* packed = (ull*)(wsb + ofs);     ofs += (size_t)B * P * sizeof(ull);

  const int S = 8;                       // face segments per row
  const int segF = (F + S - 1) / S;

  int np = B * P;
  k_init<<<(np + 255) / 256, 256, 0, stream>>>(packed, np);
  int nv = B * N;
  k_transform<<<(nv + 255) / 256, 256, 0, stream>>>(hv, cam, camn, pos, uv, N, B);
  int nf = B * F;
  k_faces<<<(nf + 255) / 256, 256, 0, stream>>>(faces, pos, uv, fh4, fa4, F, N, B);
  k_raster<<<B * 256 * S, 256, 0, stream>>>(fh4, packed, F, S, segF);
  k_sample<<<(np + 255) / 256, 256, 0, stream>>>(fh4, fa4, packed, img, (float*)d_out, F);
}